// Round 10
// baseline (518.685 us; speedup 1.0000x reference)
//
#include <hip/hip_runtime.h>
#include <cstdint>

// ---------- problem constants ----------
#define B_   2
#define S_   4096
#define D_   768
#define H_   12
#define DH_  64
#define BH_  (B_*H_)       // 24
#define M_   (B_*S_)       // 8192

typedef _Float16 fp16;
typedef __attribute__((ext_vector_type(8))) _Float16 fp16x8;
typedef __attribute__((ext_vector_type(4))) _Float16 fp16x4;
typedef __attribute__((ext_vector_type(4))) float    f32x4;

#define MFMA16(a,b,c) __builtin_amdgcn_mfma_f32_16x16x32_f16((a),(b),(c),0,0,0)

__device__ __forceinline__ float exp2_hw(float x) {
  float r; asm("v_exp_f32 %0, %1" : "=v"(r) : "v"(x)); return r;
}
__device__ __forceinline__ uint32_t pkrtz(float a, float b) {
  uint32_t r; asm("v_cvt_pkrtz_f16_f32 %0, %1, %2" : "=v"(r) : "v"(a), "v"(b));
  return r;
}

// ---------- async global->LDS, 16B ----------
__device__ __forceinline__ void gld_lds16(const void* g, void* l) {
  __builtin_amdgcn_global_load_lds(
      (const __attribute__((address_space(1))) unsigned int*)g,
      (__attribute__((address_space(3))) unsigned int*)l, 16, 0, 0);
}

// Stage a 64-row x 128-byte tile into LDS. Linear LDS dest (required by
// global_load_lds), inverse-swizzled GLOBAL source, swizzled reads.
__device__ __forceinline__ void stage64x128(const char* gbase, int pitch,
                                            char* lds, int tid) {
  const int lane = tid & 63, wv = tid >> 6;
#pragma unroll
  for (int j = 0; j < 2; ++j) {
    const int o   = (wv*2 + j)*1024 + lane*16;
    const int row = o >> 7;
    const int cb  = (o & 127) ^ ((row & 7) << 4);
    gld_lds16(gbase + (size_t)row*pitch + cb, lds + (wv*2 + j)*1024);
  }
}

// ---------- kernel 1: W transpose + hi/lo split ----------
__global__ __launch_bounds__(256) void prep_w(const float* __restrict__ wq,
                                              const float* __restrict__ wk,
                                              const float* __restrict__ wv,
                                              fp16* __restrict__ wt) {
  const int idx = blockIdx.x*256 + threadIdx.x;       // 3*768*768 total
  const int mat = idx / (768*768);
  const int e   = idx % (768*768);
  const int n   = e / 768, k = e % 768;
  const float* w = mat == 0 ? wq : (mat == 1 ? wk : wv);
  const float v = w[(size_t)k*768 + n];
  fp16* base = wt + (size_t)mat * (2*768*768);
  const fp16 hv = (fp16)v;
  base[e]            = hv;
  base[768*768 + e]  = (fp16)(v - (float)hv);
}

// ---------- kernel 2: projection GEMM (f16x3, inline split), 64x64 tile -----
__global__ __launch_bounds__(256) void proj_gemm(
    const float* __restrict__ xq, const float* __restrict__ xk,
    const float* __restrict__ xv, const fp16* __restrict__ wt,
    fp16* __restrict__ qhi, fp16* __restrict__ qlo,
    fp16* __restrict__ khi, fp16* __restrict__ klo,
    fp16* __restrict__ vtp) {
  __shared__ __align__(16) char sm[16384];
  char* sWh = sm;
  char* sWl = sm + 8192;
  const int tid = threadIdx.x, lane = tid & 63, wv = tid >> 6;
  const int c = lane & 15, g = lane >> 4;
  const int r128 = c * 128;
  const int co0 = ((c & 7) ^ g) << 4;
  const int co1 = co0 ^ 64;
  const int mb  = blockIdx.x * 64;
  const int h   = blockIdx.y;
  const int nb  = h * 64;
  const int mat = blockIdx.z;
  const float* x = mat == 0 ? xq : (mat == 1 ? xk : xv);
  const fp16* wth = wt + (size_t)mat * (2*768*768);
  const fp16* wtl = wth + 768*768;

  f32x4 acc[4] = {};
  const int xrow = mb + wv*16 + c;

  for (int k0 = 0; k0 < 768; k0 += 64) {
    __syncthreads();
    stage64x128((const char*)(wth + (size_t)nb*768 + k0), 1536, sWh, tid);
    stage64x128((const char*)(wtl + (size_t)nb*768 + k0), 1536, sWl, tid);
    __syncthreads();

    fp16x8 ah[2], al[2];
#pragma unroll
    for (int ks = 0; ks < 2; ++ks) {
      const float* xp = x + (size_t)xrow*768 + k0 + ks*32 + g*8;
      const f32x4 x0 = *(const f32x4*)xp;
      const f32x4 x1 = *(const f32x4*)(xp + 4);
#pragma unroll
      for (int j = 0; j < 8; ++j) {
        const float v = j < 4 ? x0[j] : x1[j - 4];
        const fp16 hv = (fp16)v;
        ah[ks][j] = hv;
        al[ks][j] = (fp16)(v - (float)hv);
      }
    }
#pragma unroll
    for (int ks = 0; ks < 2; ++ks)
#pragma unroll
      for (int nt = 0; nt < 4; ++nt) {
        const char* wb  = sWh + r128 + nt*2048;
        const char* wlb = sWl + r128 + nt*2048;
        const int co = ks ? co1 : co0;
        const fp16x8 bh = *(const fp16x8*)(wb  + co);
        const fp16x8 bl = *(const fp16x8*)(wlb + co);
        acc[nt] = MFMA16(ah[ks], bh, acc[nt]);
        acc[nt] = MFMA16(ah[ks], bl, acc[nt]);
        acc[nt] = MFMA16(al[ks], bh, acc[nt]);
      }
  }

  if (mat < 2) {
    fp16* ph = mat ? khi : qhi;
    fp16* pl = mat ? klo : qlo;
#pragma unroll
    for (int nt = 0; nt < 4; ++nt)
#pragma unroll
      for (int r = 0; r < 4; ++r) {
        const int m = mb + wv*16 + g*4 + r;      // C/D row = 4*(l>>4)+reg
        const int bb = m >> 12, s = m & (S_-1);
        const size_t idx = ((size_t)(bb*H_ + h)*S_ + s)*DH_ + nt*16 + c;
        const float v = acc[nt][r];
        const fp16 hv = (fp16)v;
        ph[idx] = hv;
        pl[idx] = (fp16)(v - (float)hv);
      }
  } else {
    // V: transpose 64x64 tile through LDS, store [d][s] coalesced
    __syncthreads();
    fp16* tile = (fp16*)sm;   // [64 d][64 m_local]
#pragma unroll
    for (int nt = 0; nt < 4; ++nt) {
      const int dd = nt*16 + c, ml = wv*16 + g*4;
      const fp16x4 hv = {(fp16)acc[nt][0], (fp16)acc[nt][1],
                         (fp16)acc[nt][2], (fp16)acc[nt][3]};
      *(fp16x4*)(tile + dd*64 + ml) = hv;
    }
    __syncthreads();
    const int bb = mb >> 12, s0 = mb & (S_-1);
    const int dd = tid >> 2, ml0 = (tid & 3) * 16;
    const size_t obase = ((size_t)(bb*H_ + h)*DH_ + dd)*S_ + s0 + ml0;
#pragma unroll
    for (int u = 0; u < 2; ++u)
      *(fp16x8*)(vtp + obase + u*8) = *(const fp16x8*)(tile + dd*64 + ml0 + u*8);
  }
}

// ---------- kernel 3: flash attention, pipelined ----------
// WG = one (b,h) x 128 q-rows; 4 waves x 32-q (2 subtiles of 16).
// Swapped QK^T: D[kv][q] = mfma(A=K_frag, B=Qt_frag) -> lane col = one q.
// Pipeline: K double-buffered (staged mid-iter t for t+1, hidden under PV);
// V issue-early (staged at iter top, hidden under QK^T+softmax).
// LDS 48KB -> 3 WG/CU. P strip 2KB/wave reused across the two q-subtiles.
__global__ __launch_bounds__(256) void mha_flash(
    const fp16* __restrict__ qhi, const fp16* __restrict__ qlo,
    const fp16* __restrict__ khi, const fp16* __restrict__ klo,
    const fp16* __restrict__ vt, float* __restrict__ out) {
  __shared__ __align__(16) char sm[49152];
  char* sKh0 = sm;             // K buf0 hi (8KB)
  char* sKl0 = sm + 8192;      // K buf0 lo
  char* sKh1 = sm + 16384;     // K buf1 hi
  char* sKl1 = sm + 24576;     // K buf1 lo
  char* sV   = sm + 32768;     // V (8KB, single)
  char* sP   = sm + 40960;     // 4 waves x 2KB

  const int tid = threadIdx.x, lane = tid & 63, wv = tid >> 6;
  const int c = lane & 15, g = lane >> 4;
  const int r128 = c * 128;
  const int co0 = ((c & 7) ^ g) << 4;      // == (g*16)^((c&7)<<4)
  const int co1 = co0 ^ 64;
  const int pg3 = (g & 1) << 3;
  const int pse = ((c & 7) ^ (g >> 1)) << 4;
  const int qb = blockIdx.x * 128;
  const int bh = blockIdx.y;
  const int b = bh / H_, h = bh % H_;

  // ---- prologue: Q 128 rows (hi+lo) via the 32KB K-dbuf area ----
  const size_t qoff = ((size_t)bh*S_ + qb) * DH_;
  stage64x128((const char*)(qhi + qoff),          128, sm,         tid);
  stage64x128((const char*)(qhi + qoff + 64*DH_), 128, sm +  8192, tid);
  stage64x128((const char*)(qlo + qoff),          128, sm + 16384, tid);
  stage64x128((const char*)(qlo + qoff + 64*DH_), 128, sm + 24576, tid);
  __syncthreads();

  fp16x8 qfh[2][2], qfl[2][2];
  {
    const char* hb = sm + (wv >> 1)*8192;           // Q rows (wv>>1)*64..
    const char* lb = sm + 16384 + (wv >> 1)*8192;
#pragma unroll
    for (int qs = 0; qs < 2; ++qs) {
      const int rl = ((wv & 1)*32 + qs*16 + c) * 128;   // row&7 == c&7
      qfh[qs][0] = *(const fp16x8*)(hb + rl + co0);
      qfh[qs][1] = *(const fp16x8*)(hb + rl + co1);
      qfl[qs][0] = *(const fp16x8*)(lb + rl + co0);
      qfl[qs][1] = *(const fp16x8*)(lb + rl + co1);
    }
  }
  __syncthreads();   // all waves done reading Q from the K-dbuf area

  const size_t kbase = (size_t)bh * S_ * DH_;
  const size_t vbase = (size_t)bh * DH_ * S_;
  stage64x128((const char*)(khi + kbase), 128, sKh0, tid);
  stage64x128((const char*)(klo + kbase), 128, sKl0, tid);
  __syncthreads();   // K(0) resident

  float m_run[2] = {-1e30f, -1e30f};
  float lrow[2][4] = {};
  f32x4 accO[2][4] = {};
  fp16x8 ones;
#pragma unroll
  for (int j = 0; j < 8; ++j) ones[j] = (fp16)1.0f;
  const float C2 = 0.125f * 1.4426950408889634f;   // scale * log2(e)

  for (int kt = 0; kt < S_/64; ++kt) {
    char* sKhC = (kt & 1) ? sKh1 : sKh0;
    char* sKlC = (kt & 1) ? sKl1 : sKl0;
    char* sKhN = (kt & 1) ? sKh0 : sKh1;
    char* sKlN = (kt & 1) ? sKl0 : sKl1;

    // issue-early V(t): latency hides under QK^T + softmax
    stage64x128((const char*)(vt + vbase + kt*64), S_*2, sV, tid);

    // ---- QK^T (f16x3), K frags shared across both q-subtiles ----
    f32x4 accS[2][4] = {};
    __builtin_amdgcn_s_setprio(1);
#pragma unroll
    for (int t = 0; t < 4; ++t) {
      const char* kb = sKhC + r128 + t*2048;
      const char* lb = sKlC + r128 + t*2048;
      const fp16x8 kh0 = *(const fp16x8*)(kb + co0);
      const fp16x8 kh1 = *(const fp16x8*)(kb + co1);
      const fp16x8 kl0 = *(const fp16x8*)(lb + co0);
      const fp16x8 kl1 = *(const fp16x8*)(lb + co1);
#pragma unroll
      for (int qs = 0; qs < 2; ++qs) {
        accS[qs][t] = MFMA16(kh0, qfh[qs][0], accS[qs][t]);
        accS[qs][t] = MFMA16(kh0, qfl[qs][0], accS[qs][t]);
        accS[qs][t] = MFMA16(kl0, qfh[qs][0], accS[qs][t]);
        accS[qs][t] = MFMA16(kh1, qfh[qs][1], accS[qs][t]);
        accS[qs][t] = MFMA16(kh1, qfl[qs][1], accS[qs][t]);
        accS[qs][t] = MFMA16(kl1, qfh[qs][1], accS[qs][t]);
      }
    }
    __builtin_amdgcn_s_setprio(0);

    // ---- online softmax (lane owns q = subtile*16 + c) ----
    float mx0 = -1e30f, mx1 = -1e30f;
#pragma unroll
    for (int t = 0; t < 4; ++t) {
      mx0 = fmaxf(mx0, fmaxf(fmaxf(accS[0][t][0], accS[0][t][1]),
                             fmaxf(accS[0][t][2], accS[0][t][3])));
      mx1 = fmaxf(mx1, fmaxf(fmaxf(accS[1][t][0], accS[1][t][1]),
                             fmaxf(accS[1][t][2], accS[1][t][3])));
    }
    mx0 = fmaxf(mx0, __shfl_xor(mx0, 16));
    mx0 = fmaxf(mx0, __shfl_xor(mx0, 32));
    mx1 = fmaxf(mx1, __shfl_xor(mx1, 16));
    mx1 = fmaxf(mx1, __shfl_xor(mx1, 32));

    const bool rec = (mx0 > m_run[0]) || (mx1 > m_run[1]);
    if (__any(rec)) {
#pragma unroll
      for (int qs = 0; qs < 2; ++qs) {
        const float mxq = qs ? mx1 : mx0;
        const float m_new = fmaxf(m_run[qs], mxq);
        const float corr = exp2_hw(__builtin_fmaf(m_run[qs], C2, -m_new*C2));
        m_run[qs] = m_new;
        float crow[4];
#pragma unroll
        for (int r = 0; r < 4; ++r)
          crow[r] = __shfl(corr, (lane & 48) | (g*4 + r));
#pragma unroll
        for (int r = 0; r < 4; ++r) lrow[qs][r] *= crow[r];
#pragma unroll
        for (int d = 0; d < 4; ++d)
#pragma unroll
          for (int r = 0; r < 4; ++r) accO[qs][d][r] *= crow[r];
      }
    }

    // ---- P(qs=0) -> per-wave 2KB strip (written pre-MID) ----
    char* pbase = sP + wv*2048 + r128;
    {
      const float negnm = -m_run[0]*C2;
#pragma unroll
      for (int t = 0; t < 4; ++t) {
        const float p0 = exp2_hw(__builtin_fmaf(accS[0][t][0], C2, negnm));
        const float p1 = exp2_hw(__builtin_fmaf(accS[0][t][1], C2, negnm));
        const float p2 = exp2_hw(__builtin_fmaf(accS[0][t][2], C2, negnm));
        const float p3 = exp2_hw(__builtin_fmaf(accS[0][t][3], C2, negnm));
        uint2 pw; pw.x = pkrtz(p0, p1); pw.y = pkrtz(p2, p3);
        *(uint2*)(pbase + (pg3 | (pse ^ (t*32)))) = pw;
      }
    }

    __syncthreads();   // MID: V(t) resident (drain covers only V loads)

    // prefetch K(t+1): latency hides under PV; drained at END barrier
    if (kt < S_/64 - 1) {
      stage64x128((const char*)(khi + kbase + (size_t)(kt+1)*64*DH_), 128,
                  sKhN, tid);
      stage64x128((const char*)(klo + kbase + (size_t)(kt+1)*64*DH_), 128,
                  sKlN, tid);
    }

    // ---- qs=0: P frags, row-sum via MFMA(ones), PV ----
    {
      const fp16x8 pA0 = *(const fp16x8*)(pbase + co0);
      const fp16x8 pA1 = *(const fp16x8*)(pbase + co1);
      f32x4 aL = {};
      aL = MFMA16(pA0, ones, aL);
      aL = MFMA16(pA1, ones, aL);
      __builtin_amdgcn_s_setprio(1);
#pragma unroll
      for (int d = 0; d < 4; ++d) {
        const char* vb = sV + r128 + d*2048;
        accO[0][d] = MFMA16(pA0, *(const fp16x8*)(vb + co0), accO[0][d]);
        accO[0][d] = MFMA16(pA1, *(const fp16x8*)(vb + co1), accO[0][d]);
      }
      __builtin_amdgcn_s_setprio(0);
#pragma unroll
      for (int r = 0; r < 4; ++r) lrow[0][r] += aL[r];
    }

    // ---- P(qs=1) into the same strip (wave-local WAR, lgkmcnt-ordered) ----
    {
      const float negnm = -m_run[1]*C2;
#pragma unroll
      for (int t = 0; t < 4; ++t) {
        const float p0 = exp2_hw(__builtin_fmaf(accS[1][t][0], C2, negnm));
        const float p1 = exp2_hw(__builtin_fmaf(accS[1][t][1], C2, negnm));
        const float p2 = exp2_hw(__builtin_fmaf(accS[1][t][2], C2, negnm));
        const float p3 = exp2_hw(__builtin_fmaf(accS[1][t][3], C2, negnm));
        uint2 pw; pw.x = pkrtz(p0, p1); pw.y = pkrtz(p2, p3);
        *(uint2*)(pbase + (pg3 | (pse ^ (t*32)))) = pw;
      }
      const fp16x8 pB0 = *(const fp16x8*)(pbase + co0);
      const fp16x8 pB1 = *(const fp16x8*)(pbase + co1);
      f32x4 aL = {};
      aL = MFMA16(pB0, ones, aL);
      aL = MFMA16(pB1, ones, aL);
      __builtin_amdgcn_s_setprio(1);
#pragma unroll
      for (int d = 0; d < 4; ++d) {
        const char* vb = sV + r128 + d*2048;
        accO[1][d] = MFMA16(pB0, *(const fp16x8*)(vb + co0), accO[1][d]);
        accO[1][d] = MFMA16(pB1, *(const fp16x8*)(vb + co1), accO[1][d]);
      }
      __builtin_amdgcn_s_setprio(0);
#pragma unroll
      for (int r = 0; r < 4; ++r) lrow[1][r] += aL[r];
    }

    __syncthreads();   // END: K(t+1) resident; V/P readers done (WAR safe)
  }

  // ---- epilogue: divide by l (row layout), store ----
#pragma unroll
  for (int qs = 0; qs < 2; ++qs) {
    float inv[4];
#pragma unroll
    for (int r = 0; r < 4; ++r) inv[r] = 1.f / lrow[qs][r];
    const int s0 = qb + wv*32 + qs*16 + g*4;
#pragma unroll
    for (int d = 0; d < 4; ++d)
#pragma unroll
      for (int r = 0; r < 4; ++r)
        out[((size_t)(b*S_ + s0 + r))*D_ + h*DH_ + d*16 + c] =
            accO[qs][d][r] * inv[r];
  }
}

// ---------- launch ----------
extern "C" void kernel_launch(void* const* d_in, const int* in_sizes, int n_in,
                              void* d_out, int out_size, void* d_ws, size_t ws_size,
                              hipStream_t stream) {
  const float* xq = (const float*)d_in[0];
  const float* xk = (const float*)d_in[1];
  const float* xv = (const float*)d_in[2];
  const float* wq = (const float*)d_in[3];
  const float* wk = (const float*)d_in[4];
  const float* wv = (const float*)d_in[5];
  float* out = (float*)d_out;

  // ws layout (f16): Wt (6x768x768) | Qhi Qlo Khi Klo Vt   (~70 MB)
  fp16* wt  = (fp16*)d_ws;
  fp16* qhi = wt + (size_t)6*768*768;
  const size_t PL = (size_t)BH_*S_*DH_;
  fp16* qlo = qhi + PL;
  fp16* khi = qlo + PL;
  fp16* klo = khi + PL;
  fp16* vtp = klo + PL;

  hipLaunchKernelGGL(prep_w, dim3(3*768*768/256), dim3(256), 0, stream,
                     wq, wk, wv, wt);
  hipLaunchKernelGGL(proj_gemm, dim3(M_/64, H_, 3), dim3(256), 0, stream,
                     xq, xk, xv, wt, qhi, qlo, khi, klo, vtp);
  hipLaunchKernelGGL(mha_flash, dim3(S_/128, BH_), dim3(256), 0, stream,
                     qhi, qlo, khi, klo, vtp, out);
}